// Round 11
// baseline (248.924 us; speedup 1.0000x reference)
//
#include <hip/hip_runtime.h>
#include <hip/hip_bf16.h>

typedef __bf16 bf16x8 __attribute__((ext_vector_type(8)));
typedef __bf16 bf16x4 __attribute__((ext_vector_type(4)));
typedef float  f32x4  __attribute__((ext_vector_type(4)));

#define B_  8
#define T_  2048
#define D_  1024
#define HS_ 64

// DIAGNOSTIC ROUND: qkv_fused and attn_fused bodies repeated x4 (idempotent,
// memory-clobber fenced) so their per-dispatch durations exceed the 41us
// harness fills and surface in the rocprof top-5 with counters. Math and
// outputs identical to R10. Revert the REPS next round.
#define QKV_REPS  4
#define ATTN_REPS 4

// Kernel 0: pack the three [D,HS] fp32 weights into bf16 MFMA-fragment order.
__global__ __launch_bounds__(256) void pack_w(
    const float* __restrict__ Wq, const float* __restrict__ Wk,
    const float* __restrict__ Wv, __bf16* __restrict__ Wp)
{
    const int t    = blockIdx.x * 256 + threadIdx.x;   // 0..24575
    const int lane = t & 63;
    const int pg   = t >> 6;                           // 0..383
    const int s    = pg & 3;
    const int c    = (pg >> 2) & 31;
    const int p    = pg >> 7;
    const int m16  = lane & 15;
    const int quad = lane >> 4;

    const float* W = (p == 0) ? Wq : (p == 1) ? Wk : Wv;
    const float* src = W + (size_t)(c * 32 + quad * 8) * 64 + s * 16 + m16;
    bf16x8 frag;
    #pragma unroll
    for (int j = 0; j < 8; ++j) frag[j] = (__bf16)src[(size_t)j * 64];
    *(bf16x8*)(Wp + (size_t)pg * 512 + lane * 8) = frag;
}

// Kernel 1: fused QKV projection (M=32/wave, cross-kstep ping-pong).
__global__ __launch_bounds__(256) void qkv_fused(
    const float* __restrict__ x,     // [16384][1024] fp32
    const __bf16* __restrict__ Wp,   // [384][512] fragment-packed bf16
    const float* __restrict__ bq, const float* __restrict__ bk,
    const float* __restrict__ bv,
    __bf16* __restrict__ Q,          // [8][2048][64] row-major
    __bf16* __restrict__ Kp,         // [8][32][8][64][8] frag-packed
    __bf16* __restrict__ Vp)         // [8][32][8][64][8] frag-packed
{
    __shared__ alignas(16) unsigned char Smem[73728];  // Xs(67584) ∪ Red(73728)

    const int rt   = blockIdx.x;                  // 0..511
    const int wave = threadIdx.x >> 6;            // K-slice owner
    const int lane = threadIdx.x & 63;
    const int m16  = lane & 15;
    const int quad = lane >> 4;
    const int row0 = rt * 32;

    __bf16* Xs = (__bf16*)(Smem + wave * 16896);  // 32 rows x 264 (pad 8)

    #pragma unroll 1
    for (int rep = 0; rep < QKV_REPS; ++rep) {
    asm volatile("" ::: "memory");   // force re-execution per rep

    // ---- Phase 1: stage x-slice (32 rows x 256 cols), fp32 -> bf16 ----
    {
        const float* xsrc = x + (size_t)row0 * 1024 + wave * 256;
        const int sr = lane >> 5;                 // 0..1
        const int sc = (lane & 31) * 8;           // 0..248
        #pragma unroll
        for (int i = 0; i < 16; ++i) {
            const int r = i * 2 + sr;
            f32x4 v0 = *(const f32x4*)(xsrc + (size_t)r * 1024 + sc);
            f32x4 v1 = *(const f32x4*)(xsrc + (size_t)r * 1024 + sc + 4);
            bf16x8 w;
            #pragma unroll
            for (int e = 0; e < 4; ++e) { w[e] = (__bf16)v0[e]; w[4 + e] = (__bf16)v1[e]; }
            *(bf16x8*)&Xs[r * 264 + sc] = w;
        }
    }
    __builtin_amdgcn_wave_barrier();   // pin DS write->read order (wave-local)

    // ---- Phase 2: K-loop, ping-pong Wp prefetch, 2 row-halves ----
    f32x4 acc[3][4][2];
    #pragma unroll
    for (int p = 0; p < 3; ++p)
        #pragma unroll
        for (int s = 0; s < 4; ++s)
            #pragma unroll
            for (int t = 0; t < 2; ++t) acc[p][s][t] = {0.f, 0.f, 0.f, 0.f};

    bf16x8 bfA[12], bfB[12];

#define WLOAD(BUF, K0)                                                     \
    {                                                                      \
        const int cb_ = wave * 8 + ((K0) >> 5);                            \
        _Pragma("unroll")                                                  \
        for (int ps_ = 0; ps_ < 12; ++ps_) {                               \
            const int p_ = ps_ >> 2, s_ = ps_ & 3;                         \
            BUF[ps_] = *(const bf16x8*)(Wp +                               \
                ((size_t)((p_ * 32 + cb_) * 4 + s_) << 9) + lane * 8);     \
        }                                                                  \
    }
#define KSTEP(BUF, K0)                                                     \
    {                                                                      \
        bf16x8 a0 = *(const bf16x8*)&Xs[m16 * 264 + (K0) + quad * 8];      \
        bf16x8 a1 = *(const bf16x8*)&Xs[(16 + m16) * 264 + (K0) + quad * 8]; \
        __builtin_amdgcn_sched_barrier(0);                                 \
        _Pragma("unroll")                                                  \
        for (int ps_ = 0; ps_ < 12; ++ps_) {                               \
            acc[ps_ >> 2][ps_ & 3][0] =                                    \
                __builtin_amdgcn_mfma_f32_16x16x32_bf16(a0, BUF[ps_], acc[ps_ >> 2][ps_ & 3][0], 0, 0, 0); \
            acc[ps_ >> 2][ps_ & 3][1] =                                    \
                __builtin_amdgcn_mfma_f32_16x16x32_bf16(a1, BUF[ps_], acc[ps_ >> 2][ps_ & 3][1], 0, 0, 0); \
        }                                                                  \
    }

    WLOAD(bfA, 0);                       // prologue
    #pragma unroll
    for (int k0 = 0; k0 < 256; k0 += 64) {
        WLOAD(bfB, k0 + 32);             // prefetch next while computing cur
        KSTEP(bfA, k0);
        if (k0 + 64 < 256) WLOAD(bfA, k0 + 64);
        KSTEP(bfB, k0 + 32);
    }
#undef KSTEP
#undef WLOAD

    // ---- Phase 3: cross-wave reduce (Red overlays dead Xs) + epilogue ----
    f32x4* Red = (f32x4*)Smem;                    // [3][24][64]
    __syncthreads();                              // all Xs reads done
    if (wave != 0) {
        #pragma unroll
        for (int p = 0; p < 3; ++p)
            #pragma unroll
            for (int s = 0; s < 4; ++s)
                #pragma unroll
                for (int t = 0; t < 2; ++t)
                    Red[((wave - 1) * 24 + (p * 4 + s) * 2 + t) * 64 + lane] = acc[p][s][t];
    }
    __syncthreads();
    if (wave == 0) {
        #pragma unroll
        for (int p = 0; p < 3; ++p)
            #pragma unroll
            for (int s = 0; s < 4; ++s)
                #pragma unroll
                for (int t = 0; t < 2; ++t) {
                    f32x4 sum = acc[p][s][t];
                    #pragma unroll
                    for (int w = 0; w < 3; ++w) {
                        f32x4 v = Red[(w * 24 + (p * 4 + s) * 2 + t) * 64 + lane];
                        #pragma unroll
                        for (int e = 0; e < 4; ++e) sum[e] += v[e];
                    }
                    acc[p][s][t] = sum;
                }

        #pragma unroll
        for (int t = 0; t < 2; ++t) {
            const int row0t = row0 + t * 16;

            // Q epilogue (p=0): row-major
            #pragma unroll
            for (int s = 0; s < 4; ++s) {
                const int h = s * 16 + m16;
                const float bia = bq[h];
                #pragma unroll
                for (int r = 0; r < 4; ++r)
                    Q[(size_t)(row0t + quad * 4 + r) * 64 + h] = (__bf16)(acc[0][s][t][r] + bia);
            }

            const int tb = (row0t >> 4) & 3;          // 16-row quarter in tile
            const int jt = (row0t >> 6) & 31;         // key tile
            const int bb = row0t >> 11;               // batch
            __bf16* kpt = Kp + (((size_t)bb * 32 + jt) * 8) * 512;
            __bf16* vpt = Vp + (((size_t)bb * 32 + jt) * 8) * 512;

            // K epilogue (p=1): scatter into frag-packed Kp
            {
                const int snb  = ((tb >> 1) << 1) | (quad & 1);
                const int m16b = ((tb & 1) << 3) | ((quad >> 1) << 2);  // + r
                #pragma unroll
                for (int s = 0; s < 4; ++s) {
                    const int h = s * 16 + m16;
                    const float bia = bk[h];
                    const int g     = snb * 2 + (s >> 1);
                    const int quadc = ((s & 1) << 1) | (m16 >> 3);
                    const int j     = m16 & 7;
                    #pragma unroll
                    for (int r = 0; r < 4; ++r)
                        kpt[(size_t)g * 512 + (quadc * 16 + m16b + r) * 8 + j] =
                            (__bf16)(acc[1][s][t][r] + bia);
                }
            }
            // V epilogue (p=2): frag-packed Vp, r-contiguous -> bf16x4 stores
            {
                const int lanec = ((((tb & 1) << 1) | (quad >> 1)) << 4) + m16;
                const int jbase = (quad & 1) << 2;
                #pragma unroll
                for (int s = 0; s < 4; ++s) {
                    const int h = s * 16 + m16;
                    const float bia = bv[h];
                    const int g = s * 2 + (tb >> 1);
                    bf16x4 pack;
                    #pragma unroll
                    for (int r = 0; r < 4; ++r) pack[r] = (__bf16)(acc[2][s][t][r] + bia);
                    *(bf16x4*)(vpt + (size_t)g * 512 + lanec * 8 + jbase) = pack;
                }
            }
        }
    }
    __syncthreads();   // Smem (Red/Xs overlay) safe to reuse next rep
    }  // rep
}

// Kernel 2: causal attention, fulltile scheme (as R10), body repeated x4.
__global__ __launch_bounds__(512) void attn_fused(
    const __bf16* __restrict__ Q,    // [8][2048][64]
    const __bf16* __restrict__ Kp,   // [8][32][8][64][8]
    const __bf16* __restrict__ Vp,   // [8][32][8][64][8]
    float* __restrict__ O)           // [8][2048][64] fp32
{
    __shared__ float Mrg[8][64][37];  // o_A[16], mA, lA, o_B[16], mB, lB (+pad)

    const int s  = blockIdx.x;       // fulltile pair id 0..31
    const int b  = blockIdx.y;       // batch
    const int wave = threadIdx.x >> 6;   // 0..7 (split-K slice)
    const int lane = threadIdx.x & 63;
    const int m16  = lane & 15;
    const int quad = lane >> 4;
    const float SC = 0.18033688f;    // 0.125 * log2(e)

    const __bf16* Qb = Q  + (size_t)b * T_ * HS_;
    const __bf16* Kb = Kp + (size_t)b * 32 * 4096;
    const __bf16* Vb = Vp + (size_t)b * 32 * 4096;
    float* Obase     = O  + (size_t)b * T_ * HS_;

    bf16x8 vA[8];

#define LOADK(KA, JT)                                                      \
    {                                                                      \
        const __bf16* kb_ = Kb + (size_t)(JT) * 4096 + lane * 8;           \
        _Pragma("unroll")                                                  \
        for (int g_ = 0; g_ < 8; ++g_) KA[g_] = *(const bf16x8*)(kb_ + g_ * 512); \
    }
#define LOADV(JT)                                                          \
    {                                                                      \
        const __bf16* vb_ = Vb + (size_t)(JT) * 4096 + lane * 8;           \
        _Pragma("unroll")                                                  \
        for (int g_ = 0; g_ < 8; ++g_) vA[g_] = *(const bf16x8*)(vb_ + g_ * 512); \
    }

#define STEP(CK, NK)                                                       \
    {                                                                      \
        const int j0 = jt * 64;                                            \
        LOADV(jt);                      /* V current, used after softmax */ \
        f32x4 svA[4], svB[4];                                              \
        _Pragma("unroll")                                                  \
        for (int sn_ = 0; sn_ < 4; ++sn_) {                                \
            svA[sn_] = {0.f, 0.f, 0.f, 0.f};                               \
            svB[sn_] = {0.f, 0.f, 0.f, 0.f};                               \
            svA[sn_] = __builtin_amdgcn_mfma_f32_16x16x32_bf16(CK[sn_*2],   qA0, svA[sn_], 0, 0, 0); \
            svA[sn_] = __builtin_amdgcn_mfma_f32_16x16x32_bf16(CK[sn_*2+1], qA1, svA[sn_], 0, 0, 0); \
            svB[sn_] = __builtin_amdgcn_mfma_f32_16x16x32_bf16(CK[sn_*2],   qB0, svB[sn_], 0, 0, 0); \
            svB[sn_] = __builtin_amdgcn_mfma_f32_16x16x32_bf16(CK[sn_*2+1], qB1, svB[sn_], 0, 0, 0); \
        }                                                                  \
        if (jt + 8 < ntiles) LOADK(NK, jt + 8);                            \
        __builtin_amdgcn_sched_barrier(0);                                 \
        if (jt == ntiles - 1) {   /* diagonal tile: causal mask, per half */ \
            _Pragma("unroll")                                              \
            for (int sn_ = 0; sn_ < 4; ++sn_) {                            \
                const int kbase = j0 + ((sn_ >> 1) << 5) + (quad << 3) + ((sn_ & 1) << 2); \
                _Pragma("unroll")                                          \
                for (int r_ = 0; r_ < 4; ++r_) {                           \
                    svA[sn_][r_] = (kbase + r_ <= qrowA) ? svA[sn_][r_] : -3e38f; \
                    svB[sn_][r_] = (kbase + r_ <= qrowB) ? svB[sn_][r_] : -3e38f; \
                }                                                          \
            }                                                              \
        }                                                                  \
        float mxA = -3e38f, mxB = -3e38f;                                  \
        _Pragma("unroll")                                                  \
        for (int sn_ = 0; sn_ < 4; ++sn_)                                  \
            _Pragma("unroll")                                              \
            for (int r_ = 0; r_ < 4; ++r_) {                               \
                mxA = fmaxf(mxA, svA[sn_][r_]);                            \
                mxB = fmaxf(mxB, svB[sn_][r_]);                            \
            }                                                              \
        mxA = fmaxf(mxA, __shfl_xor(mxA, 16));                             \
        mxA = fmaxf(mxA, __shfl_xor(mxA, 32));                             \
        mxB = fmaxf(mxB, __shfl_xor(mxB, 16));                             \
        mxB = fmaxf(mxB, __shfl_xor(mxB, 32));                             \
        const float newmA = fmaxf(mA, mxA);                                \
        const float newmB = fmaxf(mB, mxB);                                \
        const float alA = exp2f((mA - newmA) * SC);                        \
        const float alB = exp2f((mB - newmB) * SC);                        \
        mA = newmA; mB = newmB;                                            \
        const float nmA = newmA * SC, nmB = newmB * SC;                    \
        float rsA = 0.f, rsB = 0.f;                                        \
        _Pragma("unroll")                                                  \
        for (int sn_ = 0; sn_ < 4; ++sn_)                                  \
            _Pragma("unroll")                                              \
            for (int r_ = 0; r_ < 4; ++r_) {                               \
                float pa_ = exp2f(__builtin_fmaf(svA[sn_][r_], SC, -nmA)); \
                float pb_ = exp2f(__builtin_fmaf(svB[sn_][r_], SC, -nmB)); \
                svA[sn_][r_] = pa_; rsA += pa_;                            \
                svB[sn_][r_] = pb_; rsB += pb_;                            \
            }                                                              \
        rsA += __shfl_xor(rsA, 16); rsA += __shfl_xor(rsA, 32);            \
        rsB += __shfl_xor(rsB, 16); rsB += __shfl_xor(rsB, 32);            \
        lA = lA * alA + rsA;  lB = lB * alB + rsB;                         \
        _Pragma("unroll")                                                  \
        for (int hs_ = 0; hs_ < 4; ++hs_)                                  \
            _Pragma("unroll")                                              \
            for (int r_ = 0; r_ < 4; ++r_) {                               \
                oA[hs_][r_] *= alA;                                        \
                oB[hs_][r_] *= alB;                                        \
            }                                                              \
        bf16x8 pA0, pA1, pB0, pB1;                                         \
        _Pragma("unroll")                                                  \
        for (int r_ = 0; r_ < 4; ++r_) {                                   \
            pA0[r_]     = (__bf16)svA[0][r_];                              \
            pA0[4 + r_] = (__bf16)svA[1][r_];                              \
            pA1[r_]     = (__bf16)svA[2][r_];                              \
            pA1[4 + r_] = (__bf16)svA[3][r_];                              \
            pB0[r_]     = (__bf16)svB[0][r_];                              \
            pB0[4 + r_] = (__bf16)svB[1][r_];                              \
            pB1[r_]     = (__bf16)svB[2][r_];                              \
            pB1[4 + r_] = (__bf16)svB[3][r_];                              \
        }                                                                  \
        _Pragma("unroll")                                                  \
        for (int hs_ = 0; hs_ < 4; ++hs_) {                                \
            oA[hs_] = __builtin_amdgcn_mfma_f32_16x16x32_bf16(vA[hs_*2],   pA0, oA[hs_], 0, 0, 0); \
            oA[hs_] = __builtin_amdgcn_mfma_f32_16x16x32_bf16(vA[hs_*2+1], pA1, oA[hs_], 0, 0, 0); \
            oB[hs_] = __builtin_amdgcn_mfma_f32_16x16x32_bf16(vA[hs_*2],   pB0, oB[hs_], 0, 0, 0); \
            oB[hs_] = __builtin_amdgcn_mfma_f32_16x16x32_bf16(vA[hs_*2+1], pB1, oB[hs_], 0, 0, 0); \
        }                                                                  \
    }

    auto runPhase = [&](const int f) {
        const int ntiles = (f >> 1) + 1;          // same for both halves
        const int qrowA  = f * 32 + m16;
        const int qrowB  = qrowA + 16;

        bf16x8 qA0 = *(const bf16x8*)(Qb + (size_t)qrowA * 64 + quad * 8);
        bf16x8 qA1 = *(const bf16x8*)(Qb + (size_t)qrowA * 64 + 32 + quad * 8);
        bf16x8 qB0 = *(const bf16x8*)(Qb + (size_t)qrowB * 64 + quad * 8);
        bf16x8 qB1 = *(const bf16x8*)(Qb + (size_t)qrowB * 64 + 32 + quad * 8);

        f32x4 oA[4], oB[4];
        #pragma unroll
        for (int hs = 0; hs < 4; ++hs) {
            oA[hs] = {0.f, 0.f, 0.f, 0.f};
            oB[hs] = {0.f, 0.f, 0.f, 0.f};
        }
        float mA = -3e38f, lA = 0.f, mB = -3e38f, lB = 0.f;

        bf16x8 kA[8], kB[8];
        int jt = wave;                     // 8-way split-K by tile parity
        if (jt < ntiles) {
            LOADK(kA, jt);
            while (true) {
                STEP(kA, kB);
                jt += 8; if (jt >= ntiles) break;
                STEP(kB, kA);
                jt += 8; if (jt >= ntiles) break;
            }
        }

        // 8-way split-K merge: everyone publishes, waves 0/1 combine A/B
        #pragma unroll
        for (int hs = 0; hs < 4; ++hs)
            #pragma unroll
            for (int r = 0; r < 4; ++r) {
                Mrg[wave][lane][hs * 4 + r]      = oA[hs][r];
                Mrg[wave][lane][18 + hs * 4 + r] = oB[hs][r];
            }
        Mrg[wave][lane][16] = mA; Mrg[wave][lane][17] = lA;
        Mrg[wave][lane][34] = mB; Mrg[wave][lane][35] = lB;
        __syncthreads();
        if (wave < 2) {
            const int off  = wave * 18;
            const int qrow = f * 32 + wave * 16 + m16;
            float mw[8], lw[8];
            #pragma unroll
            for (int w = 0; w < 8; ++w) {
                mw[w] = Mrg[w][lane][off + 16];
                lw[w] = Mrg[w][lane][off + 17];
            }
            float M = mw[0];
            #pragma unroll
            for (int w = 1; w < 8; ++w) M = fmaxf(M, mw[w]);
            float aw[8], den = 0.f;
            #pragma unroll
            for (int w = 0; w < 8; ++w) {
                aw[w] = exp2f((mw[w] - M) * SC);
                den += lw[w] * aw[w];
            }
            const float inv = 1.f / den;
            float* Ob = Obase + (size_t)qrow * 64;
            #pragma unroll
            for (int hs = 0; hs < 4; ++hs) {
                f32x4 v;
                #pragma unroll
                for (int r = 0; r < 4; ++r) {
                    float acc = 0.f;
                    #pragma unroll
                    for (int w = 0; w < 8; ++w)
                        acc += Mrg[w][lane][off + hs * 4 + r] * aw[w];
                    v[r] = acc * inv;
                }
                *(f32x4*)(Ob + hs * 16 + quad * 4) = v;
            }
        }
        __syncthreads();   // Mrg reusable for next phase
    };

    #pragma unroll 1
    for (int rep = 0; rep < ATTN_REPS; ++rep) {
        asm volatile("" ::: "memory");   // force re-execution per rep
        runPhase(s);           // (s>>1)+1 tiles
        runPhase(63 - s);      // 32-(s>>1) tiles  -> 33-34 uniform per block
    }
#undef STEP
#undef LOADV
#undef LOADK
}

// ---------------------------------------------------------------------------
extern "C" void kernel_launch(void* const* d_in, const int* in_sizes, int n_in,
                              void* d_out, int out_size, void* d_ws, size_t ws_size,
                              hipStream_t stream)
{
    const float* x  = (const float*)d_in[0];
    const float* Wq = (const float*)d_in[1];
    const float* bq = (const float*)d_in[2];
    const float* Wk = (const float*)d_in[3];
    const float* bk = (const float*)d_in[4];
    const float* Wv = (const float*)d_in[5];
    const float* bv = (const float*)d_in[6];
    float* out = (float*)d_out;

    __bf16* Wp = (__bf16*)d_ws;              // 384*512 bf16         = 0.4 MB
    __bf16* Q  = Wp + 384 * 512;             // 8*2048*64 bf16       = 2 MB
    __bf16* Kp = Q  + (size_t)B_ * T_ * HS_; // frag-packed          = 2 MB
    __bf16* Vp = Kp + (size_t)B_ * T_ * HS_; // frag-packed          = 2 MB

    pack_w<<<96, 256, 0, stream>>>(Wq, Wk, Wv, Wp);
    qkv_fused<<<512, 256, 0, stream>>>(x, Wp, bq, bk, bv, Q, Kp, Vp);
    attn_fused<<<dim3(32, 8), 512, 0, stream>>>(Q, Kp, Vp, out);
}

// Round 12
// 132.202 us; speedup vs baseline: 1.8829x; 1.8829x over previous
//
#include <hip/hip_runtime.h>
#include <hip/hip_bf16.h>

typedef __bf16 bf16x8 __attribute__((ext_vector_type(8)));
typedef __bf16 bf16x4 __attribute__((ext_vector_type(4)));
typedef float  f32x4  __attribute__((ext_vector_type(4)));

#define B_  8
#define T_  2048
#define D_  1024
#define HS_ 64

// ---------------------------------------------------------------------------
// fp32 in/out; bf16 MFMA internally.
// pack_w -> qkv_fused (OUTPUT-SPLIT: wave owns 3 (p,s) pairs, full K;
//                      16 waves/CU, no reduce barrier)
//        -> attn_fused (fulltile, 8-wave split-K; byte-identical to R10).
//
// Round-21: R11 diagnostic measured qkv=25.5us (MfmaUtil 10%, VALU 7%,
// Occ 10% -> latency/occupancy-bound; NOT L2-BW) and attn=14.8us.
// K-split forced acc=96 VGPR + 72KB LDS + 2-barrier reduce -> 2 waves/SIMD.
// Output-split: acc=12 VGPR, Xs=33KB shared, no reduce; launch_bounds(256,4)
// -> 4 blocks/CU x 4 waves = 16 waves/CU. Floor max(HBM 10.6, L2 11.4)us.
// ---------------------------------------------------------------------------

// Kernel 0: pack the three [D,HS] fp32 weights into bf16 MFMA-fragment order.
__global__ __launch_bounds__(256) void pack_w(
    const float* __restrict__ Wq, const float* __restrict__ Wk,
    const float* __restrict__ Wv, __bf16* __restrict__ Wp)
{
    const int t    = blockIdx.x * 256 + threadIdx.x;   // 0..24575
    const int lane = t & 63;
    const int pg   = t >> 6;                           // 0..383
    const int s    = pg & 3;
    const int c    = (pg >> 2) & 31;
    const int p    = pg >> 7;
    const int m16  = lane & 15;
    const int quad = lane >> 4;

    const float* W = (p == 0) ? Wq : (p == 1) ? Wk : Wv;
    const float* src = W + (size_t)(c * 32 + quad * 8) * 64 + s * 16 + m16;
    bf16x8 frag;
    #pragma unroll
    for (int j = 0; j < 8; ++j) frag[j] = (__bf16)src[(size_t)j * 64];
    *(bf16x8*)(Wp + (size_t)pg * 512 + lane * 8) = frag;
}

// Kernel 1: fused QKV projection, output-split across waves.
// grid = 1024 blocks (16 rows each), block = 256 = 4 waves.
// Xs = 16x1024 bf16 staged cooperatively (33KB); wave w computes pairs
// ps = 3w..3w+2 over the FULL K=1024 (32 ksteps x {1 ds_read + 3 Wp loads
// + 3 MFMA}, ping-pong distance-2 prefetch). No cross-wave reduce.
__global__ __launch_bounds__(256, 4) void qkv_fused(
    const float* __restrict__ x,     // [16384][1024] fp32
    const __bf16* __restrict__ Wp,   // [384][512] fragment-packed bf16
    const float* __restrict__ bq, const float* __restrict__ bk,
    const float* __restrict__ bv,
    __bf16* __restrict__ Q,          // [8][2048][64] row-major
    __bf16* __restrict__ Kp,         // [8][32][8][64][8] frag-packed
    __bf16* __restrict__ Vp)         // [8][32][8][64][8] frag-packed
{
    __shared__ alignas(16) __bf16 Xs[16 * 1032];   // 33,024 B (pad 8)

    const int rt   = blockIdx.x;                  // 0..1023
    const int wave = threadIdx.x >> 6;
    const int lane = threadIdx.x & 63;
    const int m16  = lane & 15;
    const int quad = lane >> 4;
    const int row0 = rt * 16;

    // ---- Phase 1: cooperative stage 16 rows x 1024 cols, fp32 -> bf16 ----
    // wave w stages column slice [w*256, w*256+256) of all 16 rows.
    {
        const float* xsrc = x + (size_t)row0 * 1024 + wave * 256;
        const int sr = lane >> 5;                 // 0..1
        const int sc = (lane & 31) * 8;           // 0..248
        #pragma unroll
        for (int i = 0; i < 8; ++i) {
            const int r = i * 2 + sr;
            f32x4 v0 = *(const f32x4*)(xsrc + (size_t)r * 1024 + sc);
            f32x4 v1 = *(const f32x4*)(xsrc + (size_t)r * 1024 + sc + 4);
            bf16x8 w;
            #pragma unroll
            for (int e = 0; e < 4; ++e) { w[e] = (__bf16)v0[e]; w[4 + e] = (__bf16)v1[e]; }
            *(bf16x8*)&Xs[r * 1032 + wave * 256 + sc] = w;
        }
    }
    __syncthreads();                  // Xs shared across waves now

    // ---- Phase 2: full-K loop, 3 output pairs per wave ----
    const int ps0 = wave * 3;
    const __bf16* wb[3];
    #pragma unroll
    for (int j = 0; j < 3; ++j) {
        const int ps = ps0 + j, p = ps >> 2, s = ps & 3;
        wb[j] = Wp + (size_t)p * 65536 + s * 512 + lane * 8;   // + c*2048
    }
    const __bf16* ab = &Xs[m16 * 1032 + quad * 8];             // + c*32

    f32x4 acc[3];
    #pragma unroll
    for (int j = 0; j < 3; ++j) acc[j] = {0.f, 0.f, 0.f, 0.f};

    bf16x8 bfA[3], bfB[3];

#define WLOAD(BUF, C)                                                      \
    {                                                                      \
        _Pragma("unroll")                                                  \
        for (int j_ = 0; j_ < 3; ++j_)                                     \
            BUF[j_] = *(const bf16x8*)(wb[j_] + (size_t)(C) * 2048);       \
    }
#define KSTEP(BUF, C)                                                      \
    {                                                                      \
        bf16x8 a_ = *(const bf16x8*)(ab + (C) * 32);                       \
        __builtin_amdgcn_sched_barrier(0);                                 \
        _Pragma("unroll")                                                  \
        for (int j_ = 0; j_ < 3; ++j_)                                     \
            acc[j_] = __builtin_amdgcn_mfma_f32_16x16x32_bf16(a_, BUF[j_], acc[j_], 0, 0, 0); \
    }

    WLOAD(bfA, 0);
    WLOAD(bfB, 1);
    #pragma unroll
    for (int c = 0; c < 32; c += 2) {
        KSTEP(bfA, c);
        if (c + 2 < 32) WLOAD(bfA, c + 2);   // refill after consumption
        KSTEP(bfB, c + 1);
        if (c + 3 < 32) WLOAD(bfB, c + 3);
    }
#undef KSTEP
#undef WLOAD

    // ---- Phase 3: per-wave epilogue (formulas verified R7-R10) ----
    const int tb = (row0 >> 4) & 3;               // 16-row quarter in tile
    const int jt = (row0 >> 6) & 31;              // key tile
    const int bb = row0 >> 11;                    // batch

    #pragma unroll
    for (int j = 0; j < 3; ++j) {
        const int ps = ps0 + j, p = ps >> 2, s = ps & 3;
        const int h = s * 16 + m16;
        if (p == 0) {                 // Q: row-major
            const float bia = bq[h];
            #pragma unroll
            for (int r = 0; r < 4; ++r)
                Q[(size_t)(row0 + quad * 4 + r) * 64 + h] = (__bf16)(acc[j][r] + bia);
        } else if (p == 1) {          // K: scatter into frag-packed Kp
            __bf16* kpt = Kp + (((size_t)bb * 32 + jt) * 8) * 512;
            const int snb   = ((tb >> 1) << 1) | (quad & 1);
            const int m16b  = ((tb & 1) << 3) | ((quad >> 1) << 2);
            const int g     = snb * 2 + (s >> 1);
            const int quadc = ((s & 1) << 1) | (m16 >> 3);
            const int jj    = m16 & 7;
            const float bia = bk[h];
            #pragma unroll
            for (int r = 0; r < 4; ++r)
                kpt[(size_t)g * 512 + (quadc * 16 + m16b + r) * 8 + jj] =
                    (__bf16)(acc[j][r] + bia);
        } else {                      // V: frag-packed Vp, bf16x4 store
            __bf16* vpt = Vp + (((size_t)bb * 32 + jt) * 8) * 512;
            const int lanec = ((((tb & 1) << 1) | (quad >> 1)) << 4) + m16;
            const int jbase = (quad & 1) << 2;
            const int g     = s * 2 + (tb >> 1);
            const float bia = bv[h];
            bf16x4 pack;
            #pragma unroll
            for (int r = 0; r < 4; ++r) pack[r] = (__bf16)(acc[j][r] + bia);
            *(bf16x4*)(vpt + (size_t)g * 512 + lanec * 8 + jbase) = pack;
        }
    }
}

// Kernel 2: causal attention, fulltile scheme (byte-identical to R10).
// grid (32,8) x 512 thr (8 waves). Block s owns fulltiles fA=s, fB=63-s.
__global__ __launch_bounds__(512) void attn_fused(
    const __bf16* __restrict__ Q,    // [8][2048][64]
    const __bf16* __restrict__ Kp,   // [8][32][8][64][8]
    const __bf16* __restrict__ Vp,   // [8][32][8][64][8]
    float* __restrict__ O)           // [8][2048][64] fp32
{
    __shared__ float Mrg[8][64][37];  // o_A[16], mA, lA, o_B[16], mB, lB (+pad)

    const int s  = blockIdx.x;       // fulltile pair id 0..31
    const int b  = blockIdx.y;       // batch
    const int wave = threadIdx.x >> 6;   // 0..7 (split-K slice)
    const int lane = threadIdx.x & 63;
    const int m16  = lane & 15;
    const int quad = lane >> 4;
    const float SC = 0.18033688f;    // 0.125 * log2(e)

    const __bf16* Qb = Q  + (size_t)b * T_ * HS_;
    const __bf16* Kb = Kp + (size_t)b * 32 * 4096;
    const __bf16* Vb = Vp + (size_t)b * 32 * 4096;
    float* Obase     = O  + (size_t)b * T_ * HS_;

    bf16x8 vA[8];

#define LOADK(KA, JT)                                                      \
    {                                                                      \
        const __bf16* kb_ = Kb + (size_t)(JT) * 4096 + lane * 8;           \
        _Pragma("unroll")                                                  \
        for (int g_ = 0; g_ < 8; ++g_) KA[g_] = *(const bf16x8*)(kb_ + g_ * 512); \
    }
#define LOADV(JT)                                                          \
    {                                                                      \
        const __bf16* vb_ = Vb + (size_t)(JT) * 4096 + lane * 8;           \
        _Pragma("unroll")                                                  \
        for (int g_ = 0; g_ < 8; ++g_) vA[g_] = *(const bf16x8*)(vb_ + g_ * 512); \
    }

#define STEP(CK, NK)                                                       \
    {                                                                      \
        const int j0 = jt * 64;                                            \
        LOADV(jt);                      /* V current, used after softmax */ \
        f32x4 svA[4], svB[4];                                              \
        _Pragma("unroll")                                                  \
        for (int sn_ = 0; sn_ < 4; ++sn_) {                                \
            svA[sn_] = {0.f, 0.f, 0.f, 0.f};                               \
            svB[sn_] = {0.f, 0.f, 0.f, 0.f};                               \
            svA[sn_] = __builtin_amdgcn_mfma_f32_16x16x32_bf16(CK[sn_*2],   qA0, svA[sn_], 0, 0, 0); \
            svA[sn_] = __builtin_amdgcn_mfma_f32_16x16x32_bf16(CK[sn_*2+1], qA1, svA[sn_], 0, 0, 0); \
            svB[sn_] = __builtin_amdgcn_mfma_f32_16x16x32_bf16(CK[sn_*2],   qB0, svB[sn_], 0, 0, 0); \
            svB[sn_] = __builtin_amdgcn_mfma_f32_16x16x32_bf16(CK[sn_*2+1], qB1, svB[sn_], 0, 0, 0); \
        }                                                                  \
        if (jt + 8 < ntiles) LOADK(NK, jt + 8);                            \
        __builtin_amdgcn_sched_barrier(0);                                 \
        if (jt == ntiles - 1) {   /* diagonal tile: causal mask, per half */ \
            _Pragma("unroll")                                              \
            for (int sn_ = 0; sn_ < 4; ++sn_) {                            \
                const int kbase = j0 + ((sn_ >> 1) << 5) + (quad << 3) + ((sn_ & 1) << 2); \
                _Pragma("unroll")                                          \
                for (int r_ = 0; r_ < 4; ++r_) {                           \
                    svA[sn_][r_] = (kbase + r_ <= qrowA) ? svA[sn_][r_] : -3e38f; \
                    svB[sn_][r_] = (kbase + r_ <= qrowB) ? svB[sn_][r_] : -3e38f; \
                }                                                          \
            }                                                              \
        }                                                                  \
        float mxA = -3e38f, mxB = -3e38f;                                  \
        _Pragma("unroll")                                                  \
        for (int sn_ = 0; sn_ < 4; ++sn_)                                  \
            _Pragma("unroll")                                              \
            for (int r_ = 0; r_ < 4; ++r_) {                               \
                mxA = fmaxf(mxA, svA[sn_][r_]);                            \
                mxB = fmaxf(mxB, svB[sn_][r_]);                            \
            }                                                              \
        mxA = fmaxf(mxA, __shfl_xor(mxA, 16));                             \
        mxA = fmaxf(mxA, __shfl_xor(mxA, 32));                             \
        mxB = fmaxf(mxB, __shfl_xor(mxB, 16));                             \
        mxB = fmaxf(mxB, __shfl_xor(mxB, 32));                             \
        const float newmA = fmaxf(mA, mxA);                                \
        const float newmB = fmaxf(mB, mxB);                                \
        const float alA = exp2f((mA - newmA) * SC);                        \
        const float alB = exp2f((mB - newmB) * SC);                        \
        mA = newmA; mB = newmB;                                            \
        const float nmA = newmA * SC, nmB = newmB * SC;                    \
        float rsA = 0.f, rsB = 0.f;                                        \
        _Pragma("unroll")                                                  \
        for (int sn_ = 0; sn_ < 4; ++sn_)                                  \
            _Pragma("unroll")                                              \
            for (int r_ = 0; r_ < 4; ++r_) {                               \
                float pa_ = exp2f(__builtin_fmaf(svA[sn_][r_], SC, -nmA)); \
                float pb_ = exp2f(__builtin_fmaf(svB[sn_][r_], SC, -nmB)); \
                svA[sn_][r_] = pa_; rsA += pa_;                            \
                svB[sn_][r_] = pb_; rsB += pb_;                            \
            }                                                              \
        rsA += __shfl_xor(rsA, 16); rsA += __shfl_xor(rsA, 32);            \
        rsB += __shfl_xor(rsB, 16); rsB += __shfl_xor(rsB, 32);            \
        lA = lA * alA + rsA;  lB = lB * alB + rsB;                         \
        _Pragma("unroll")                                                  \
        for (int hs_ = 0; hs_ < 4; ++hs_)                                  \
            _Pragma("unroll")                                              \
            for (int r_ = 0; r_ < 4; ++r_) {                               \
                oA[hs_][r_] *= alA;                                        \
                oB[hs_][r_] *= alB;                                        \
            }                                                              \
        bf16x8 pA0, pA1, pB0, pB1;                                         \
        _Pragma("unroll")                                                  \
        for (int r_ = 0; r_ < 4; ++r_) {                                   \
            pA0[r_]     = (__bf16)svA[0][r_];                              \
            pA0[4 + r_] = (__bf16)svA[1][r_];                              \
            pA1[r_]     = (__bf16)svA[2][r_];                              \
            pA1[4 + r_] = (__bf16)svA[3][r_];                              \
            pB0[r_]     = (__bf16)svB[0][r_];                              \
            pB0[4 + r_] = (__bf16)svB[1][r_];                              \
            pB1[r_]     = (__bf16)svB[2][r_];                              \
            pB1[4 + r_] = (__bf16)svB[3][r_];                              \
        }                                                                  \
        _Pragma("unroll")                                                  \
        for (int hs_ = 0; hs_ < 4; ++hs_) {                                \
            oA[hs_] = __builtin_amdgcn_mfma_f32_16x16x32_bf16(vA[hs_*2],   pA0, oA[hs_], 0, 0, 0); \
            oA[hs_] = __builtin_amdgcn_mfma_f32_16x16x32_bf16(vA[hs_*2+1], pA1, oA[hs_], 0, 0, 0); \
            oB[hs_] = __builtin_amdgcn_mfma_f32_16x16x32_bf16(vA[hs_*2],   pB0, oB[hs_], 0, 0, 0); \
            oB[hs_] = __builtin_amdgcn_mfma_f32_16x16x32_bf16(vA[hs_*2+1], pB1, oB[hs_], 0, 0, 0); \
        }                                                                  \
    }

    auto runPhase = [&](const int f) {
        const int ntiles = (f >> 1) + 1;          // same for both halves
        const int qrowA  = f * 32 + m16;
        const int qrowB  = qrowA + 16;

        bf16x8 qA0 = *(const bf16x8*)(Qb + (size_t)qrowA * 64 + quad * 8);
        bf16x8 qA1 = *(const bf16x8*)(Qb + (size_t)qrowA * 64 + 32 + quad * 8);
        bf16x8 qB0 = *(const bf16x8*)(Qb + (size_t)qrowB * 64 + quad * 8);
        bf16x8 qB1 = *(const bf16x8*)(Qb + (size_t)qrowB * 64 + 32 + quad * 8);

        f32x4 oA[4], oB[4];
        #pragma unroll
        for (int hs = 0; hs < 4; ++hs) {
            oA[hs] = {0.f, 0.f, 0.f, 0.f};
            oB[hs] = {0.f, 0.f, 0.f, 0.f};
        }
        float mA = -3e38f, lA = 0.f, mB = -3e38f, lB = 0.f;

        bf16x8 kA[8], kB[8];
        int jt = wave;                     // 8-way split-K by tile parity
        if (jt < ntiles) {
            LOADK(kA, jt);
            while (true) {
                STEP(kA, kB);
                jt += 8; if (jt >= ntiles) break;
                STEP(kB, kA);
                jt += 8; if (jt >= ntiles) break;
            }
        }

        // 8-way split-K merge: everyone publishes, waves 0/1 combine A/B
        #pragma unroll
        for (int hs = 0; hs < 4; ++hs)
            #pragma unroll
            for (int r = 0; r < 4; ++r) {
                Mrg[wave][lane][hs * 4 + r]      = oA[hs][r];
                Mrg[wave][lane][18 + hs * 4 + r] = oB[hs][r];
            }
        Mrg[wave][lane][16] = mA; Mrg[wave][lane][17] = lA;
        Mrg[wave][lane][34] = mB; Mrg[wave][lane][35] = lB;
        __syncthreads();
        if (wave < 2) {
            const int off  = wave * 18;
            const int qrow = f * 32 + wave * 16 + m16;
            float mw[8], lw[8];
            #pragma unroll
            for (int w = 0; w < 8; ++w) {
                mw[w] = Mrg[w][lane][off + 16];
                lw[w] = Mrg[w][lane][off + 17];
            }
            float M = mw[0];
            #pragma unroll
            for (int w = 1; w < 8; ++w) M = fmaxf(M, mw[w]);
            float aw[8], den = 0.f;
            #pragma unroll
            for (int w = 0; w < 8; ++w) {
                aw[w] = exp2f((mw[w] - M) * SC);
                den += lw[w] * aw[w];
            }
            const float inv = 1.f / den;
            float* Ob = Obase + (size_t)qrow * 64;
            #pragma unroll
            for (int hs = 0; hs < 4; ++hs) {
                f32x4 v;
                #pragma unroll
                for (int r = 0; r < 4; ++r) {
                    float acc = 0.f;
                    #pragma unroll
                    for (int w = 0; w < 8; ++w)
                        acc += Mrg[w][lane][off + hs * 4 + r] * aw[w];
                    v[r] = acc * inv;
                }
                *(f32x4*)(Ob + hs * 16 + quad * 4) = v;
            }
        }
        __syncthreads();   // Mrg reusable for next phase
    };

    runPhase(s);           // (s>>1)+1 tiles
    runPhase(63 - s);      // 32-(s>>1) tiles  -> 33-34 uniform per block
#undef STEP
#undef LOADV
#undef LOADK
}

// ---------------------------------------------------------------------------
extern "C" void kernel_launch(void* const* d_in, const int* in_sizes, int n_in,
                              void* d_out, int out_size, void* d_ws, size_t ws_size,
                              hipStream_t stream)
{
    const float* x  = (const float*)d_in[0];
    const float* Wq = (const float*)d_in[1];
    const float* bq = (const float*)d_in[2];
    const float* Wk = (const float*)d_in[3];
    const float* bk = (const float*)d_in[4];
    const float* Wv = (const float*)d_in[5];
    const float* bv = (const float*)d_in[6];
    float* out = (float*)d_out;

    __bf16* Wp = (__bf16*)d_ws;              // 384*512 bf16         = 0.4 MB
    __bf16* Q  = Wp + 384 * 512;             // 8*2048*64 bf16       = 2 MB
    __bf16* Kp = Q  + (size_t)B_ * T_ * HS_; // frag-packed          = 2 MB
    __bf16* Vp = Kp + (size_t)B_ * T_ * HS_; // frag-packed          = 2 MB

    pack_w<<<96, 256, 0, stream>>>(Wq, Wk, Wv, Wp);
    qkv_fused<<<1024, 256, 0, stream>>>(x, Wp, bq, bk, bv, Q, Kp, Vp);
    attn_fused<<<dim3(32, 8), 512, 0, stream>>>(Q, Kp, Vp, out);
}